// Round 1
// baseline (425.963 us; speedup 1.0000x reference)
//
#include <hip/hip_runtime.h>

using f32x4  = __attribute__((ext_vector_type(4))) float;
using bf16x8 = __attribute__((ext_vector_type(8))) short;
typedef unsigned short u16;

__device__ __forceinline__ u16 f2bf(float f) {
  unsigned u = __float_as_uint(f);
  unsigned r = (u + 0x7FFFu + ((u >> 16) & 1u)) >> 16;
  return (u16)r;
}

// ---------------- Kernel 1: 1x1 convs -> featB [b][n][8], featC [b][n][8], featD bf16 [b][c][n]
__global__ void __launch_bounds__(256) k1_conv1x1(
    const float* __restrict__ x, const float* __restrict__ wB, const float* __restrict__ bB,
    const float* __restrict__ wC, const float* __restrict__ bC,
    const float* __restrict__ wD, const float* __restrict__ bD,
    float* __restrict__ featB, float* __restrict__ featC, u16* __restrict__ featD) {
  __shared__ float W[2048];
  __shared__ float Bias[32];
  const int t = threadIdx.x;
  const int b = blockIdx.y;
  const int z = blockIdx.z;
  const int n = blockIdx.x * 256 + t;
  if (z == 0) {
    for (int i = t; i < 512; i += 256) W[i] = wB[i];
    for (int i = t; i < 512; i += 256) W[512 + i] = wC[i];
    if (t < 8) Bias[t] = bB[t];
    if (t >= 8 && t < 16) Bias[t] = bC[t - 8];
  } else {
    const float* wsrc = wD + (z - 1) * 2048;
    for (int i = t; i < 2048; i += 256) W[i] = wsrc[i];
    if (t < 32) Bias[t] = bD[(z - 1) * 32 + t];
  }
  __syncthreads();
  float xv[64];
#pragma unroll
  for (int c = 0; c < 64; ++c) xv[c] = x[((b * 64 + c) << 12) + n];
  if (z == 0) {
    float o[16];
#pragma unroll
    for (int k = 0; k < 16; ++k) {
      f32x4 s = {0.f, 0.f, 0.f, 0.f};
#pragma unroll
      for (int cq = 0; cq < 16; ++cq) {
        f32x4 wv = *(const f32x4*)&W[k * 64 + cq * 4];
        f32x4 xq = {xv[cq * 4], xv[cq * 4 + 1], xv[cq * 4 + 2], xv[cq * 4 + 3]};
        s += wv * xq;
      }
      o[k] = Bias[k] + s[0] + s[1] + s[2] + s[3];
    }
    int base = ((b << 12) + n) * 8;
    f32x4 v0 = {o[0], o[1], o[2], o[3]};
    f32x4 v1 = {o[4], o[5], o[6], o[7]};
    f32x4 v2 = {o[8], o[9], o[10], o[11]};
    f32x4 v3 = {o[12], o[13], o[14], o[15]};
    *(f32x4*)&featB[base] = v0;
    *(f32x4*)&featB[base + 4] = v1;
    *(f32x4*)&featC[base] = v2;
    *(f32x4*)&featC[base + 4] = v3;
  } else {
#pragma unroll 4
    for (int k = 0; k < 32; ++k) {
      f32x4 s = {0.f, 0.f, 0.f, 0.f};
#pragma unroll
      for (int cq = 0; cq < 16; ++cq) {
        f32x4 wv = *(const f32x4*)&W[k * 64 + cq * 4];
        f32x4 xq = {xv[cq * 4], xv[cq * 4 + 1], xv[cq * 4 + 2], xv[cq * 4 + 3]};
        s += wv * xq;
      }
      float val = Bias[k] + s[0] + s[1] + s[2] + s[3];
      featD[((b * 64 + (z - 1) * 32 + k) << 12) + n] = f2bf(val);
    }
  }
}

// ---------------- Kernel 2: PAM fused attention (no-max softmax), bf16 MFMA.
// Block: 256 thr (4 waves), one (batch, 64-query tile). x1 = alpha*feat_e + x.
__global__ void __launch_bounds__(256) k2_pam(
    const float* __restrict__ fB, const float* __restrict__ fC, const u16* __restrict__ fD,
    const float* __restrict__ x, const float* __restrict__ alpha, float* __restrict__ x1) {
  __shared__ u16 Qs[64 * 32];   // [q][k] bf16, k>=8 zero
  __shared__ u16 Ks[64 * 32];   // [m][k] bf16, k>=8 zero
  __shared__ u16 Ps[64 * 72];   // [q][m] bf16, row stride 72
  __shared__ float dens[64];
  const int t = threadIdx.x;
  const int b = blockIdx.y;
  const int n0 = blockIdx.x * 64;
  const int w = t >> 6, lane = t & 63, quad = lane >> 4, l16 = lane & 15;
  for (int i = t; i < 2048; i += 256) { Qs[i] = 0; Ks[i] = 0; }
  if (t < 64) dens[t] = 0.f;
  __syncthreads();
  {
    int q = t >> 2, dw = t & 3;
    const float* p = fB + ((b << 12) + n0 + q) * 8 + dw * 2;
    *(unsigned*)&Qs[q * 32 + dw * 2] = (unsigned)f2bf(p[0]) | ((unsigned)f2bf(p[1]) << 16);
  }
  f32x4 accN[4];
  float denp[4];
#pragma unroll
  for (int j = 0; j < 4; ++j) { accN[j] = (f32x4){0.f, 0.f, 0.f, 0.f}; denp[j] = 0.f; }

  for (int mc = 0; mc < 64; ++mc) {
    const int m0 = mc * 64;
    __syncthreads();                      // prev PV done; Qs fill visible (first iter)
    {
      int m = t >> 2, dw = t & 3;
      const float* p = fC + ((b << 12) + m0 + m) * 8 + dw * 2;
      *(unsigned*)&Ks[m * 32 + dw * 2] = (unsigned)f2bf(p[0]) | ((unsigned)f2bf(p[1]) << 16);
    }
    __syncthreads();                      // Ks ready
    // S = K * Q^T : wave w owns m-rows [w*16, w*16+16)
    bf16x8 af = *(const bf16x8*)&Ks[(w * 16 + l16) * 32 + quad * 8];
#pragma unroll
    for (int j = 0; j < 4; ++j) {
      bf16x8 bfr = *(const bf16x8*)&Qs[(j * 16 + l16) * 32 + quad * 8];
      f32x4 zero = {0.f, 0.f, 0.f, 0.f};
      f32x4 s = __builtin_amdgcn_mfma_f32_16x16x32_bf16(af, bfr, zero, 0, 0, 0);
      float psum = 0.f;
#pragma unroll
      for (int r = 0; r < 4; ++r) {
        float pv = __expf(s[r]);
        psum += pv;
        int mm = w * 16 + quad * 4 + r;   // m-local
        Ps[(j * 16 + l16) * 72 + mm] = f2bf(pv);
      }
      psum += __shfl_xor(psum, 16);
      psum += __shfl_xor(psum, 32);
      denp[j] += psum;
    }
    __syncthreads();                      // Ps ready
    // PV: num[c][q] += D[c][m] * P[m][q]; wave w owns c-rows [w*16, w*16+16)
    const u16* Abase = fD + ((b * 64 + w * 16 + l16) << 12) + m0 + quad * 8;
#pragma unroll
    for (int ks = 0; ks < 2; ++ks) {
      bf16x8 av = *(const bf16x8*)(Abase + ks * 32);
#pragma unroll
      for (int j = 0; j < 4; ++j) {
        bf16x8 bv = *(const bf16x8*)&Ps[(j * 16 + l16) * 72 + ks * 32 + quad * 8];
        accN[j] = __builtin_amdgcn_mfma_f32_16x16x32_bf16(av, bv, accN[j], 0, 0, 0);
      }
    }
  }
  if (quad == 0) {
#pragma unroll
    for (int j = 0; j < 4; ++j) atomicAdd(&dens[j * 16 + l16], denp[j]);
  }
  __syncthreads();
  const float av = alpha[0];
#pragma unroll
  for (int j = 0; j < 4; ++j) {
    float dv = dens[j * 16 + l16];
    float inv = 1.f / dv;
#pragma unroll
    for (int r = 0; r < 4; ++r) {
      int c = w * 16 + quad * 4 + r;
      int n = n0 + j * 16 + l16;
      int idx = ((b * 64 + c) << 12) + n;
      x1[idx] = av * (accN[j][r] * inv) + x[idx];
    }
  }
}

// ---------------- Kernel 3: CAM gram partials: attPart[b][cx][c][d] over 128-n chunk (fp32)
__global__ void __launch_bounds__(256) k3_gram(const float* __restrict__ x1, float* __restrict__ attPart) {
  __shared__ float X[64 * 132];
  const int t = threadIdx.x, b = blockIdx.y, cx = blockIdx.x;
  const int n0 = cx * 128;
  for (int idx = t; idx < 64 * 128; idx += 256) {
    int row = idx >> 7, col = idx & 127;
    X[row * 132 + col] = x1[((b * 64 + row) << 12) + n0 + col];
  }
  __syncthreads();
  const int cg = t >> 4, dg = t & 15;
  f32x4 acc[4][4];
#pragma unroll
  for (int i = 0; i < 4; ++i)
#pragma unroll
    for (int k = 0; k < 4; ++k) acc[i][k] = (f32x4){0.f, 0.f, 0.f, 0.f};
  for (int nq0 = 0; nq0 < 32; ++nq0) {
    int nq = (nq0 + dg) & 31;   // rotate to spread LDS banks
    f32x4 a[4], bb[4];
#pragma unroll
    for (int i = 0; i < 4; ++i) a[i] = *(const f32x4*)&X[(cg * 4 + i) * 132 + nq * 4];
#pragma unroll
    for (int k = 0; k < 4; ++k) bb[k] = *(const f32x4*)&X[(dg * 4 + k) * 132 + nq * 4];
#pragma unroll
    for (int i = 0; i < 4; ++i)
#pragma unroll
      for (int k = 0; k < 4; ++k) acc[i][k] += a[i] * bb[k];
  }
#pragma unroll
  for (int i = 0; i < 4; ++i)
#pragma unroll
    for (int k = 0; k < 4; ++k) {
      f32x4 s = acc[i][k];
      attPart[((b * 32 + cx) * 64 + cg * 4 + i) * 64 + dg * 4 + k] = s[0] + s[1] + s[2] + s[3];
    }
}

// ---------------- Kernel 4: CAM softmax of (rowmax - att) == softmax(rowmin - att) form (stable)
__global__ void __launch_bounds__(256) k4_softmax(const float* __restrict__ attPart, float* __restrict__ attP) {
  const int b = blockIdx.x, t = threadIdx.x;
  const int c = t >> 2, dg = t & 3;
  float v[16];
#pragma unroll
  for (int i = 0; i < 16; ++i) v[i] = 0.f;
  for (int p = 0; p < 32; ++p) {
    const float* src = &attPart[((b * 32 + p) * 64 + c) * 64 + dg * 16];
#pragma unroll
    for (int i = 0; i < 16; ++i) v[i] += src[i];
  }
  float mn = v[0];
#pragma unroll
  for (int i = 1; i < 16; ++i) mn = fminf(mn, v[i]);
  mn = fminf(mn, __shfl_xor(mn, 1));
  mn = fminf(mn, __shfl_xor(mn, 2));
  float pv[16];
  float sum = 0.f;
#pragma unroll
  for (int i = 0; i < 16; ++i) { pv[i] = __expf(mn - v[i]); sum += pv[i]; }
  sum += __shfl_xor(sum, 1);
  sum += __shfl_xor(sum, 2);
  float inv = 1.f / sum;
#pragma unroll
  for (int i = 0; i < 16; ++i) attP[(b * 64 + c) * 64 + dg * 16 + i] = pv[i] * inv;
}

// ---------------- Kernel 5: x2 = beta * (attP @ x1) + x1
__global__ void __launch_bounds__(256) k5_apply(const float* __restrict__ attP, const float* __restrict__ x1,
                                                const float* __restrict__ beta, float* __restrict__ x2) {
  __shared__ float A[64 * 68];
  const int t = threadIdx.x, b = blockIdx.y;
  const int n = blockIdx.x * 256 + t;
  for (int idx = t; idx < 4096; idx += 256) A[(idx >> 6) * 68 + (idx & 63)] = attP[(b << 12) + idx];
  __syncthreads();
  float xv[64];
#pragma unroll
  for (int d = 0; d < 64; ++d) xv[d] = x1[((b * 64 + d) << 12) + n];
  const float bv = beta[0];
#pragma unroll 4
  for (int c = 0; c < 64; ++c) {
    f32x4 s = {0.f, 0.f, 0.f, 0.f};
#pragma unroll
    for (int dq = 0; dq < 16; ++dq) {
      f32x4 avv = *(const f32x4*)&A[c * 68 + dq * 4];
      f32x4 xq = {xv[dq * 4], xv[dq * 4 + 1], xv[dq * 4 + 2], xv[dq * 4 + 3]};
      s += avv * xq;
    }
    float fe = s[0] + s[1] + s[2] + s[3];
    x2[((b * 64 + c) << 12) + n] = bv * fe + xv[c];
  }
}

// ---------------- Kernel 6: conv3x3 (64->128, pad 1) + bias -> y [b][128][64][64]
__global__ void __launch_bounds__(256) k6_conv(const float* __restrict__ x2, const float* __restrict__ cw,
                                               const float* __restrict__ cbias, float* __restrict__ y) {
  __shared__ float xt[8 * 18 * 34];   // [ic][iy][ix]
  __shared__ float wt[72 * 32];       // [ic*9+kk][oc]
  const int b = blockIdx.z, ocg = blockIdx.y;
  const int th = blockIdx.x >> 1, tw = blockIdx.x & 1;
  const int h0 = th * 16, w0 = tw * 32;
  const int t = threadIdx.x, tx = t & 31, ty = t >> 5;   // ty 0..7
  const int oc0 = ocg * 32;
  f32x4 acc0[8], acc1[8];
#pragma unroll
  for (int o = 0; o < 8; ++o) { acc0[o] = (f32x4){0.f, 0.f, 0.f, 0.f}; acc1[o] = (f32x4){0.f, 0.f, 0.f, 0.f}; }
  for (int icc = 0; icc < 8; ++icc) {
    const int ic0 = icc * 8;
    __syncthreads();
    for (int idx = t; idx < 4896; idx += 256) {
      int ic = idx / 612, r = idx - ic * 612;
      int iy = r / 34, ix = r - iy * 34;
      int gy = h0 - 1 + iy, gx = w0 - 1 + ix;
      float v = 0.f;
      if (gy >= 0 && gy < 64 && gx >= 0 && gx < 64)
        v = x2[((b * 64 + ic0 + ic) << 12) + gy * 64 + gx];
      xt[idx] = v;
    }
    for (int idx = t; idx < 2304; idx += 256) {
      int oc = idx & 31, r = idx >> 5;  // r = ic*9 + kk
      wt[r * 32 + oc] = cw[(oc0 + oc) * 576 + ic0 * 9 + r];
    }
    __syncthreads();
    for (int ic = 0; ic < 8; ++ic) {
#pragma unroll
      for (int ky = 0; ky < 3; ++ky)
#pragma unroll
        for (int kx = 0; kx < 3; ++kx) {
          float xv0 = xt[ic * 612 + (ty + ky) * 34 + tx + kx];
          float xv1 = xt[ic * 612 + (ty + 8 + ky) * 34 + tx + kx];
          const float* wp = &wt[(ic * 9 + ky * 3 + kx) * 32];
#pragma unroll
          for (int o = 0; o < 8; ++o) {
            f32x4 wv = *(const f32x4*)(wp + o * 4);
            acc0[o] += wv * xv0;
            acc1[o] += wv * xv1;
          }
        }
    }
  }
#pragma unroll
  for (int o = 0; o < 8; ++o)
#pragma unroll
    for (int l = 0; l < 4; ++l) {
      int oc = oc0 + o * 4 + l;
      float bias = cbias[oc];
      y[((b * 128 + oc) << 12) + (h0 + ty) * 64 + w0 + tx] = acc0[o][l] + bias;
      y[((b * 128 + oc) << 12) + (h0 + ty + 8) * 64 + w0 + tx] = acc1[o][l] + bias;
    }
}

// ---------------- Kernel 7: BN batch stats -> per-channel scale/shift
__global__ void __launch_bounds__(256) k7_stats(const float* __restrict__ y, const float* __restrict__ gamma,
                                                const float* __restrict__ bbeta, float* __restrict__ bnS,
                                                float* __restrict__ bnB) {
  const int ch = blockIdx.x, t = threadIdx.x;
  float s = 0.f, ss = 0.f;
  for (int b = 0; b < 8; ++b) {
    const float* p = y + ((b * 128 + ch) << 12);
#pragma unroll
    for (int i = 0; i < 16; ++i) { float v = p[i * 256 + t]; s += v; ss += v * v; }
  }
#pragma unroll
  for (int off = 1; off < 64; off <<= 1) { s += __shfl_xor(s, off); ss += __shfl_xor(ss, off); }
  __shared__ float rs[4], rss[4];
  if ((t & 63) == 0) { rs[t >> 6] = s; rss[t >> 6] = ss; }
  __syncthreads();
  if (t == 0) {
    float S = rs[0] + rs[1] + rs[2] + rs[3];
    float SS = rss[0] + rss[1] + rss[2] + rss[3];
    float mean = S * (1.f / 32768.f);
    float var = SS * (1.f / 32768.f) - mean * mean;
    float sc = gamma[ch] * rsqrtf(var + 1e-5f);
    bnS[ch] = sc;
    bnB[ch] = bbeta[ch] - mean * sc;
  }
}

// ---------------- Kernel 8: BN apply + ReLU + maxpool(2,2, hpad=1) -> out [b][128][33][32]
__global__ void __launch_bounds__(256) k8_pool(const float* __restrict__ y, const float* __restrict__ bnS,
                                               const float* __restrict__ bnB, float* __restrict__ out) {
  const int bc = blockIdx.x;  // b*128 + ch
  const float sc = bnS[bc & 127], sh = bnB[bc & 127];
  const float* p = y + (bc << 12);
  float* op = out + bc * (33 * 32);
  for (int i = threadIdx.x; i < 33 * 32; i += 256) {
    int oh = i >> 5, ow = i & 31;
    int r0 = 2 * oh - 1, r1 = 2 * oh;
    float m = 0.f;  // ReLU floor; -inf padding excluded automatically
    if (r0 >= 0) {
      m = fmaxf(m, p[r0 * 64 + 2 * ow] * sc + sh);
      m = fmaxf(m, p[r0 * 64 + 2 * ow + 1] * sc + sh);
    }
    if (r1 <= 63) {
      m = fmaxf(m, p[r1 * 64 + 2 * ow] * sc + sh);
      m = fmaxf(m, p[r1 * 64 + 2 * ow + 1] * sc + sh);
    }
    op[i] = m;
  }
}

extern "C" void kernel_launch(void* const* d_in, const int* in_sizes, int n_in,
                              void* d_out, int out_size, void* d_ws, size_t ws_size,
                              hipStream_t stream) {
  const float* x      = (const float*)d_in[0];
  const float* wB     = (const float*)d_in[1];
  const float* bB     = (const float*)d_in[2];
  const float* wC     = (const float*)d_in[3];
  const float* bC     = (const float*)d_in[4];
  const float* wD     = (const float*)d_in[5];
  const float* bD     = (const float*)d_in[6];
  const float* alpha  = (const float*)d_in[7];
  const float* beta   = (const float*)d_in[8];
  const float* cw     = (const float*)d_in[9];
  const float* cbias  = (const float*)d_in[10];
  const float* gamma  = (const float*)d_in[11];
  const float* bnbeta = (const float*)d_in[12];

  char* ws = (char*)d_ws;
  float* featB   = (float*)(ws + 0);          // 1 MB
  float* featC   = (float*)(ws + 1048576);    // 1 MB
  u16*   featD   = (u16*)  (ws + 2097152);    // 4 MB (bf16)
  float* x1      = (float*)(ws + 6291456);    // 8 MB
  float* attPart = (float*)(ws + 14680064);   // 4 MB
  float* attP    = (float*)(ws + 18874368);   // 128 KB
  float* x2      = (float*)(ws + 19005440);   // 8 MB
  float* y       = (float*)(ws + 27394048);   // 16 MB
  float* bnS     = (float*)(ws + 44171264);
  float* bnB2    = (float*)(ws + 44171264 + 512);
  float* outp    = (float*)d_out;

  k1_conv1x1<<<dim3(16, 8, 3), 256, 0, stream>>>(x, wB, bB, wC, bC, wD, bD, featB, featC, featD);
  k2_pam<<<dim3(64, 8), 256, 0, stream>>>(featB, featC, featD, x, alpha, x1);
  k3_gram<<<dim3(32, 8), 256, 0, stream>>>(x1, attPart);
  k4_softmax<<<dim3(8), 256, 0, stream>>>(attPart, attP);
  k5_apply<<<dim3(16, 8), 256, 0, stream>>>(attP, x1, beta, x2);
  k6_conv<<<dim3(8, 4, 8), 256, 0, stream>>>(x2, cw, cbias, y);
  k7_stats<<<dim3(128), 256, 0, stream>>>(y, gamma, bnbeta, bnS, bnB2);
  k8_pool<<<dim3(1024), 256, 0, stream>>>(y, bnS, bnB2, outp);
}

// Round 2
// 309.529 us; speedup vs baseline: 1.3762x; 1.3762x over previous
//
#include <hip/hip_runtime.h>

using f32x4  = __attribute__((ext_vector_type(4))) float;
using bf16x8 = __attribute__((ext_vector_type(8))) short;
using u32x4  = __attribute__((ext_vector_type(4))) unsigned int;
typedef unsigned short u16;

__device__ __forceinline__ u16 f2bf(float f) {
  unsigned u = __float_as_uint(f);
  unsigned r = (u + 0x7FFFu + ((u >> 16) & 1u)) >> 16;
  return (u16)r;
}

// ---------------- Kernel 1: 1x1 convs -> featB [b][n][8], featC [b][n][8], featD bf16 [b][c][n]
__global__ void __launch_bounds__(256) k1_conv1x1(
    const float* __restrict__ x, const float* __restrict__ wB, const float* __restrict__ bB,
    const float* __restrict__ wC, const float* __restrict__ bC,
    const float* __restrict__ wD, const float* __restrict__ bD,
    float* __restrict__ featB, float* __restrict__ featC, u16* __restrict__ featD) {
  __shared__ float W[2048];
  __shared__ float Bias[32];
  const int t = threadIdx.x;
  const int b = blockIdx.y;
  const int z = blockIdx.z;
  const int n = blockIdx.x * 256 + t;
  if (z == 0) {
    for (int i = t; i < 512; i += 256) W[i] = wB[i];
    for (int i = t; i < 512; i += 256) W[512 + i] = wC[i];
    if (t < 8) Bias[t] = bB[t];
    if (t >= 8 && t < 16) Bias[t] = bC[t - 8];
  } else {
    const float* wsrc = wD + (z - 1) * 2048;
    for (int i = t; i < 2048; i += 256) W[i] = wsrc[i];
    if (t < 32) Bias[t] = bD[(z - 1) * 32 + t];
  }
  __syncthreads();
  float xv[64];
#pragma unroll
  for (int c = 0; c < 64; ++c) xv[c] = x[((b * 64 + c) << 12) + n];
  if (z == 0) {
    float o[16];
#pragma unroll
    for (int k = 0; k < 16; ++k) {
      f32x4 s = {0.f, 0.f, 0.f, 0.f};
#pragma unroll
      for (int cq = 0; cq < 16; ++cq) {
        f32x4 wv = *(const f32x4*)&W[k * 64 + cq * 4];
        f32x4 xq = {xv[cq * 4], xv[cq * 4 + 1], xv[cq * 4 + 2], xv[cq * 4 + 3]};
        s += wv * xq;
      }
      o[k] = Bias[k] + s[0] + s[1] + s[2] + s[3];
    }
    int base = ((b << 12) + n) * 8;
    f32x4 v0 = {o[0], o[1], o[2], o[3]};
    f32x4 v1 = {o[4], o[5], o[6], o[7]};
    f32x4 v2 = {o[8], o[9], o[10], o[11]};
    f32x4 v3 = {o[12], o[13], o[14], o[15]};
    *(f32x4*)&featB[base] = v0;
    *(f32x4*)&featB[base + 4] = v1;
    *(f32x4*)&featC[base] = v2;
    *(f32x4*)&featC[base + 4] = v3;
  } else {
#pragma unroll 4
    for (int k = 0; k < 32; ++k) {
      f32x4 s = {0.f, 0.f, 0.f, 0.f};
#pragma unroll
      for (int cq = 0; cq < 16; ++cq) {
        f32x4 wv = *(const f32x4*)&W[k * 64 + cq * 4];
        f32x4 xq = {xv[cq * 4], xv[cq * 4 + 1], xv[cq * 4 + 2], xv[cq * 4 + 3]};
        s += wv * xq;
      }
      float val = Bias[k] + s[0] + s[1] + s[2] + s[3];
      featD[((b * 64 + (z - 1) * 32 + k) << 12) + n] = f2bf(val);
    }
  }
}

// ---------------- Kernel 2: PAM fused attention (no-max softmax), bf16 MFMA.
__global__ void __launch_bounds__(256) k2_pam(
    const float* __restrict__ fB, const float* __restrict__ fC, const u16* __restrict__ fD,
    const float* __restrict__ x, const float* __restrict__ alpha, float* __restrict__ x1) {
  __shared__ u16 Qs[64 * 32];   // [q][k] bf16, k>=8 zero
  __shared__ u16 Ks[64 * 32];   // [m][k] bf16, k>=8 zero
  __shared__ u16 Ps[64 * 72];   // [q][m] bf16, row stride 72
  __shared__ float dens[64];
  const int t = threadIdx.x;
  const int b = blockIdx.y;
  const int n0 = blockIdx.x * 64;
  const int w = t >> 6, lane = t & 63, quad = lane >> 4, l16 = lane & 15;
  for (int i = t; i < 2048; i += 256) { Qs[i] = 0; Ks[i] = 0; }
  if (t < 64) dens[t] = 0.f;
  __syncthreads();
  {
    int q = t >> 2, dw = t & 3;
    const float* p = fB + ((b << 12) + n0 + q) * 8 + dw * 2;
    *(unsigned*)&Qs[q * 32 + dw * 2] = (unsigned)f2bf(p[0]) | ((unsigned)f2bf(p[1]) << 16);
  }
  f32x4 accN[4];
  float denp[4];
#pragma unroll
  for (int j = 0; j < 4; ++j) { accN[j] = (f32x4){0.f, 0.f, 0.f, 0.f}; denp[j] = 0.f; }

  for (int mc = 0; mc < 64; ++mc) {
    const int m0 = mc * 64;
    __syncthreads();
    {
      int m = t >> 2, dw = t & 3;
      const float* p = fC + ((b << 12) + m0 + m) * 8 + dw * 2;
      *(unsigned*)&Ks[m * 32 + dw * 2] = (unsigned)f2bf(p[0]) | ((unsigned)f2bf(p[1]) << 16);
    }
    __syncthreads();
    bf16x8 af = *(const bf16x8*)&Ks[(w * 16 + l16) * 32 + quad * 8];
#pragma unroll
    for (int j = 0; j < 4; ++j) {
      bf16x8 bfr = *(const bf16x8*)&Qs[(j * 16 + l16) * 32 + quad * 8];
      f32x4 zero = {0.f, 0.f, 0.f, 0.f};
      f32x4 s = __builtin_amdgcn_mfma_f32_16x16x32_bf16(af, bfr, zero, 0, 0, 0);
      float psum = 0.f;
#pragma unroll
      for (int r = 0; r < 4; ++r) {
        float pv = __expf(s[r]);
        psum += pv;
        int mm = w * 16 + quad * 4 + r;
        Ps[(j * 16 + l16) * 72 + mm] = f2bf(pv);
      }
      psum += __shfl_xor(psum, 16);
      psum += __shfl_xor(psum, 32);
      denp[j] += psum;
    }
    __syncthreads();
    const u16* Abase = fD + ((b * 64 + w * 16 + l16) << 12) + m0 + quad * 8;
#pragma unroll
    for (int ks = 0; ks < 2; ++ks) {
      bf16x8 av = *(const bf16x8*)(Abase + ks * 32);
#pragma unroll
      for (int j = 0; j < 4; ++j) {
        bf16x8 bv = *(const bf16x8*)&Ps[(j * 16 + l16) * 72 + ks * 32 + quad * 8];
        accN[j] = __builtin_amdgcn_mfma_f32_16x16x32_bf16(av, bv, accN[j], 0, 0, 0);
      }
    }
  }
  if (quad == 0) {
#pragma unroll
    for (int j = 0; j < 4; ++j) atomicAdd(&dens[j * 16 + l16], denp[j]);
  }
  __syncthreads();
  const float av = alpha[0];
#pragma unroll
  for (int j = 0; j < 4; ++j) {
    float dv = dens[j * 16 + l16];
    float inv = 1.f / dv;
#pragma unroll
    for (int r = 0; r < 4; ++r) {
      int c = w * 16 + quad * 4 + r;
      int n = n0 + j * 16 + l16;
      int idx = ((b * 64 + c) << 12) + n;
      x1[idx] = av * (accN[j][r] * inv) + x[idx];
    }
  }
}

// ---------------- Kernel 3: CAM gram partials over 128-n chunks (fp32)
__global__ void __launch_bounds__(256) k3_gram(const float* __restrict__ x1, float* __restrict__ attPart) {
  __shared__ float X[64 * 132];
  const int t = threadIdx.x, b = blockIdx.y, cx = blockIdx.x;
  const int n0 = cx * 128;
  for (int idx = t; idx < 64 * 128; idx += 256) {
    int row = idx >> 7, col = idx & 127;
    X[row * 132 + col] = x1[((b * 64 + row) << 12) + n0 + col];
  }
  __syncthreads();
  const int cg = t >> 4, dg = t & 15;
  f32x4 acc[4][4];
#pragma unroll
  for (int i = 0; i < 4; ++i)
#pragma unroll
    for (int k = 0; k < 4; ++k) acc[i][k] = (f32x4){0.f, 0.f, 0.f, 0.f};
  for (int nq0 = 0; nq0 < 32; ++nq0) {
    int nq = (nq0 + dg) & 31;
    f32x4 a[4], bb[4];
#pragma unroll
    for (int i = 0; i < 4; ++i) a[i] = *(const f32x4*)&X[(cg * 4 + i) * 132 + nq * 4];
#pragma unroll
    for (int k = 0; k < 4; ++k) bb[k] = *(const f32x4*)&X[(dg * 4 + k) * 132 + nq * 4];
#pragma unroll
    for (int i = 0; i < 4; ++i)
#pragma unroll
      for (int k = 0; k < 4; ++k) acc[i][k] += a[i] * bb[k];
  }
#pragma unroll
  for (int i = 0; i < 4; ++i)
#pragma unroll
    for (int k = 0; k < 4; ++k) {
      f32x4 s = acc[i][k];
      attPart[((b * 32 + cx) * 64 + cg * 4 + i) * 64 + dg * 4 + k] = s[0] + s[1] + s[2] + s[3];
    }
}

// ---------------- Kernel 4: CAM softmax (stable, min-form)
__global__ void __launch_bounds__(256) k4_softmax(const float* __restrict__ attPart, float* __restrict__ attP) {
  const int b = blockIdx.x, t = threadIdx.x;
  const int c = t >> 2, dg = t & 3;
  float v[16];
#pragma unroll
  for (int i = 0; i < 16; ++i) v[i] = 0.f;
  for (int p = 0; p < 32; ++p) {
    const float* src = &attPart[((b * 32 + p) * 64 + c) * 64 + dg * 16];
#pragma unroll
    for (int i = 0; i < 16; ++i) v[i] += src[i];
  }
  float mn = v[0];
#pragma unroll
  for (int i = 1; i < 16; ++i) mn = fminf(mn, v[i]);
  mn = fminf(mn, __shfl_xor(mn, 1));
  mn = fminf(mn, __shfl_xor(mn, 2));
  float pv[16];
  float sum = 0.f;
#pragma unroll
  for (int i = 0; i < 16; ++i) { pv[i] = __expf(mn - v[i]); sum += pv[i]; }
  sum += __shfl_xor(sum, 1);
  sum += __shfl_xor(sum, 2);
  float inv = 1.f / sum;
#pragma unroll
  for (int i = 0; i < 16; ++i) attP[(b * 64 + c) * 64 + dg * 16 + i] = pv[i] * inv;
}

// ---------------- Kernel 5: x2 = beta*(attP @ x1) + x1, written as bf16 NHWC [b][n][c]
__global__ void __launch_bounds__(256) k5_apply(const float* __restrict__ attP, const float* __restrict__ x1,
                                                const float* __restrict__ beta, u16* __restrict__ x2b) {
  __shared__ float A[64 * 68];
  const int t = threadIdx.x, b = blockIdx.y;
  const int n = blockIdx.x * 256 + t;
  for (int idx = t; idx < 4096; idx += 256) A[(idx >> 6) * 68 + (idx & 63)] = attP[(b << 12) + idx];
  __syncthreads();
  float xv[64];
#pragma unroll
  for (int d = 0; d < 64; ++d) xv[d] = x1[((b * 64 + d) << 12) + n];
  const float bv = beta[0];
  u16* orow = x2b + (((size_t)(b << 12) + n) << 6);
#pragma unroll 2
  for (int cg = 0; cg < 8; ++cg) {
    unsigned pk[4];
#pragma unroll
    for (int ci = 0; ci < 8; ++ci) {
      int c = cg * 8 + ci;
      f32x4 s = {0.f, 0.f, 0.f, 0.f};
#pragma unroll
      for (int dq = 0; dq < 16; ++dq) {
        f32x4 avv = *(const f32x4*)&A[c * 68 + dq * 4];
        f32x4 xq = {xv[dq * 4], xv[dq * 4 + 1], xv[dq * 4 + 2], xv[dq * 4 + 3]};
        s += avv * xq;
      }
      float fe = s[0] + s[1] + s[2] + s[3];
      float val = bv * fe + xv[c];
      unsigned h = f2bf(val);
      if ((ci & 1) == 0) pk[ci >> 1] = h;
      else pk[ci >> 1] |= h << 16;
    }
    *(u32x4*)&orow[cg * 8] = (u32x4){pk[0], pk[1], pk[2], pk[3]};
  }
}

// ---------------- Kernel W: convert conv weights fp32 [oc][ic][3][3] -> bf16 [tap][oc][ic]
__global__ void __launch_bounds__(256) kw_cvt(const float* __restrict__ cw, u16* __restrict__ wb) {
  int i = blockIdx.x * 256 + threadIdx.x;   // 73728 total
  int tap = i >> 13;                        // /(128*64)
  int rem = i & 8191;
  wb[i] = f2bf(cw[rem * 9 + tap]);          // rem = oc*64+ic
}

// ---------------- Kernel 6: conv3x3 via bf16 MFMA (9 shifted K=64 GEMMs), no bias (BN cancels it)
__global__ void __launch_bounds__(256) k6_mfma(const u16* __restrict__ x2b, const u16* __restrict__ wb,
                                               float* __restrict__ y) {
  __shared__ u16 Xl[3 * 66 * 72];           // [r*66+c][ic], ic-stride 72 (2-way bank alias = free)
  const int t = threadIdx.x, b = blockIdx.y, h = blockIdx.x;
  // stage rows h-1..h+1, cols -1..64 (zeros at halo), NHWC source
  for (int idx = t; idx < 3 * 66 * 8; idx += 256) {
    int r = idx / 528;
    int rem = idx - r * 528;
    int c = rem >> 3, icq = rem & 7;
    int gy = h - 1 + r, gx = c - 1;
    u32x4 v = {0u, 0u, 0u, 0u};
    if (gy >= 0 && gy < 64 && gx >= 0 && gx < 64)
      v = *(const u32x4*)&x2b[(((size_t)(b << 6 | gy) << 6) + gx) * 64 + icq * 8];
    *(u32x4*)&Xl[(r * 66 + c) * 72 + icq * 8] = v;
  }
  __syncthreads();
  const int w = t >> 6, lane = t & 63, quad = lane >> 4, l16 = lane & 15;
  const int mBase = (w & 1) * 64;           // oc base (4 tiles of 16)
  const int nBase = (w >> 1) * 32;          // pixel base (2 tiles of 16)
  f32x4 acc[4][2];
#pragma unroll
  for (int ot = 0; ot < 4; ++ot)
#pragma unroll
    for (int nt = 0; nt < 2; ++nt) acc[ot][nt] = (f32x4){0.f, 0.f, 0.f, 0.f};
#pragma unroll 3
  for (int tap = 0; tap < 9; ++tap) {
    const int dy = tap / 3, dx = tap - dy * 3;
    bf16x8 af[4][2];
#pragma unroll
    for (int ot = 0; ot < 4; ++ot)
#pragma unroll
      for (int kc = 0; kc < 2; ++kc)
        af[ot][kc] = *(const bf16x8*)&wb[((tap * 128 + mBase + ot * 16 + l16) << 6) + kc * 32 + quad * 8];
#pragma unroll
    for (int nt = 0; nt < 2; ++nt) {
      const int prow = dy * 66 + nBase + nt * 16 + l16 + dx;   // c = pix + dx (pix in 0..63, c 0..65)
#pragma unroll
      for (int kc = 0; kc < 2; ++kc) {
        bf16x8 bv = *(const bf16x8*)&Xl[prow * 72 + kc * 32 + quad * 8];
#pragma unroll
        for (int ot = 0; ot < 4; ++ot)
          acc[ot][nt] = __builtin_amdgcn_mfma_f32_16x16x32_bf16(af[ot][kc], bv, acc[ot][nt], 0, 0, 0);
      }
    }
  }
#pragma unroll
  for (int ot = 0; ot < 4; ++ot)
#pragma unroll
    for (int nt = 0; nt < 2; ++nt)
#pragma unroll
      for (int r = 0; r < 4; ++r) {
        int oc = mBase + ot * 16 + quad * 4 + r;
        int pix = nBase + nt * 16 + l16;
        y[((b * 128 + oc) << 12) + (h << 6) + pix] = acc[ot][nt][r];
      }
}

// ---------------- Kernel 7: BN batch stats -> per-channel scale/shift
__global__ void __launch_bounds__(256) k7_stats(const float* __restrict__ y, const float* __restrict__ gamma,
                                                const float* __restrict__ bbeta, float* __restrict__ bnS,
                                                float* __restrict__ bnB) {
  const int ch = blockIdx.x, t = threadIdx.x;
  float s = 0.f, ss = 0.f;
  for (int b = 0; b < 8; ++b) {
    const float* p = y + ((b * 128 + ch) << 12);
#pragma unroll
    for (int i = 0; i < 16; ++i) { float v = p[i * 256 + t]; s += v; ss += v * v; }
  }
#pragma unroll
  for (int off = 1; off < 64; off <<= 1) { s += __shfl_xor(s, off); ss += __shfl_xor(ss, off); }
  __shared__ float rs[4], rss[4];
  if ((t & 63) == 0) { rs[t >> 6] = s; rss[t >> 6] = ss; }
  __syncthreads();
  if (t == 0) {
    float S = rs[0] + rs[1] + rs[2] + rs[3];
    float SS = rss[0] + rss[1] + rss[2] + rss[3];
    float mean = S * (1.f / 32768.f);
    float var = SS * (1.f / 32768.f) - mean * mean;
    float sc = gamma[ch] * rsqrtf(var + 1e-5f);
    bnS[ch] = sc;
    bnB[ch] = bbeta[ch] - mean * sc;
  }
}

// ---------------- Kernel 8: BN apply + ReLU + maxpool(2,2, hpad=1) -> out [b][128][33][32]
__global__ void __launch_bounds__(256) k8_pool(const float* __restrict__ y, const float* __restrict__ bnS,
                                               const float* __restrict__ bnB, float* __restrict__ out) {
  const int bc = blockIdx.x;
  const float sc = bnS[bc & 127], sh = bnB[bc & 127];
  const float* p = y + (bc << 12);
  float* op = out + bc * (33 * 32);
  for (int i = threadIdx.x; i < 33 * 32; i += 256) {
    int oh = i >> 5, ow = i & 31;
    int r0 = 2 * oh - 1, r1 = 2 * oh;
    float m = 0.f;
    if (r0 >= 0) {
      m = fmaxf(m, p[r0 * 64 + 2 * ow] * sc + sh);
      m = fmaxf(m, p[r0 * 64 + 2 * ow + 1] * sc + sh);
    }
    if (r1 <= 63) {
      m = fmaxf(m, p[r1 * 64 + 2 * ow] * sc + sh);
      m = fmaxf(m, p[r1 * 64 + 2 * ow + 1] * sc + sh);
    }
    op[i] = m;
  }
}

extern "C" void kernel_launch(void* const* d_in, const int* in_sizes, int n_in,
                              void* d_out, int out_size, void* d_ws, size_t ws_size,
                              hipStream_t stream) {
  const float* x      = (const float*)d_in[0];
  const float* wB     = (const float*)d_in[1];
  const float* bB     = (const float*)d_in[2];
  const float* wC     = (const float*)d_in[3];
  const float* bC     = (const float*)d_in[4];
  const float* wD     = (const float*)d_in[5];
  const float* bD     = (const float*)d_in[6];
  const float* alpha  = (const float*)d_in[7];
  const float* beta   = (const float*)d_in[8];
  const float* cw     = (const float*)d_in[9];
  const float* gamma  = (const float*)d_in[11];
  const float* bnbeta = (const float*)d_in[12];

  char* ws = (char*)d_ws;
  float* featB   = (float*)(ws + 0);          // 1 MB
  float* featC   = (float*)(ws + 1048576);    // 1 MB
  u16*   featD   = (u16*)  (ws + 2097152);    // 4 MB
  float* x1      = (float*)(ws + 6291456);    // 8 MB
  float* attPart = (float*)(ws + 14680064);   // 4 MB
  float* attP    = (float*)(ws + 18874368);   // 128 KB
  u16*   x2b     = (u16*)  (ws + 19005440);   // 4 MB (bf16 NHWC)
  u16*   wb      = (u16*)  (ws + 23199744);   // 144 KB (bf16 [tap][oc][ic])
  float* y       = (float*)(ws + 23347200);   // 16 MB
  float* bnS     = (float*)(ws + 40124416);
  float* bnB2    = (float*)(ws + 40124928);
  float* outp    = (float*)d_out;

  kw_cvt<<<dim3(288), 256, 0, stream>>>(cw, wb);
  k1_conv1x1<<<dim3(16, 8, 3), 256, 0, stream>>>(x, wB, bB, wC, bC, wD, bD, featB, featC, featD);
  k2_pam<<<dim3(64, 8), 256, 0, stream>>>(featB, featC, featD, x, alpha, x1);
  k3_gram<<<dim3(32, 8), 256, 0, stream>>>(x1, attPart);
  k4_softmax<<<dim3(8), 256, 0, stream>>>(attPart, attP);
  k5_apply<<<dim3(16, 8), 256, 0, stream>>>(attP, x1, beta, x2b);
  k6_mfma<<<dim3(64, 8), 256, 0, stream>>>(x2b, wb, y);
  k7_stats<<<dim3(128), 256, 0, stream>>>(y, gamma, bnbeta, bnS, bnB2);
  k8_pool<<<dim3(1024), 256, 0, stream>>>(y, bnS, bnB2, outp);
}